// Round 16
// baseline (251.595 us; speedup 1.0000x reference)
//
#include <hip/hip_runtime.h>

typedef unsigned short u16;
typedef unsigned long long u64;
typedef __attribute__((ext_vector_type(8))) short short8;
typedef __attribute__((ext_vector_type(4))) float f32x4;

#define B_ 32
#define T_ 576
#define H_ 16
#define G_ 4
#define HD_ 64
#define DM 1024
#define NQKV 1536
#define BT (B_*T_)
#define GRID2D 24
#define FD 16

__device__ __forceinline__ u16 f2bf(float f) {
  unsigned u = __float_as_uint(f);
  u = (u + 0x7FFFu + ((u >> 16) & 1u)) >> 16;
  return (u16)u;
}
__device__ __forceinline__ float exp2v(float x) {
  float r;
  asm("v_exp_f32 %0, %1" : "=v"(r) : "v"(x));
  return r;
}

__device__ __forceinline__ void gl_lds16(const u16* g, u16* lds) {
  __builtin_amdgcn_global_load_lds((const __attribute__((address_space(1))) unsigned int*)g,
                                   (__attribute__((address_space(3))) unsigned int*)lds, 16, 0, 0);
}

// fenced wait: nothing may be scheduled across the waitcnt+barrier (rule #18 / r4-vs-r6 A/B)
#define WAITBAR(N)                                        \
  __builtin_amdgcn_sched_barrier(0);                      \
  asm volatile("s_waitcnt vmcnt(" #N ")\n\ts_barrier" ::: "memory"); \
  __builtin_amdgcn_sched_barrier(0);

// ---------------- fused prep: fp32->bf16 (x, w_qkv, w_o) + RoPE table, one launch ----------------
__device__ __forceinline__ void cvt4(const float4* __restrict__ in, u16* __restrict__ o, int i) {
  float4 v = in[i];
  u64 pk = (u64)f2bf(v.x) | ((u64)f2bf(v.y) << 16) | ((u64)f2bf(v.z) << 32) | ((u64)f2bf(v.w) << 48);
  *(u64*)(o + (size_t)i * 4) = pk;
}

#define NX4 (BT*DM/4)
#define NQ4 (NQKV*DM/4)
#define NW4 (DM*DM/4)

__global__ __launch_bounds__(256) void prep_kernel(const float4* __restrict__ x, const float4* __restrict__ wq,
                                                   const float4* __restrict__ wo,
                                                   u16* __restrict__ xb, u16* __restrict__ wqb,
                                                   u16* __restrict__ wob, float4* __restrict__ tab) {
  int i = blockIdx.x * 256 + threadIdx.x;
  if (i < NX4) { cvt4(x, xb, i); return; }
  i -= NX4;
  if (i < NQ4) { cvt4(wq, wqb, i); return; }
  i -= NQ4;
  if (i < NW4) { cvt4(wo, wob, i); return; }
  i -= NW4;
  if (i >= T_ * FD) return;
  int t = i >> 4, j = i & 15;
  float inv = powf(10000.0f, -(float)j / 16.0f);
  float tx = (float)(t / GRID2D) * inv;
  float ty = (float)(t % GRID2D) * inv;
  float4 r;
  r.x = sinf(tx); r.y = cosf(tx); r.z = sinf(ty); r.w = cosf(ty);
  tab[i] = r;
}

// ---------------- staging helper ----------------
__device__ __forceinline__ void stage_ab(const u16* __restrict__ A, const u16* __restrict__ Bw,
                                         int m0, int n0, int k0, u16* Asb, u16* Bsb,
                                         int w, int srow, int skk) {
#pragma unroll
  for (int ii = 0; ii < 2; ++ii) {
    int i = w * 2 + ii;
    int row = i * 16 + srow;
    gl_lds16(A + (size_t)(m0 + row) * DM + k0 + skk, Asb + i * 512);
    gl_lds16(Bw + (size_t)(n0 + row) * DM + k0 + skk, Bsb + i * 512);
  }
}

// ---------------- bf16 NT GEMM, 128x128 tile, BK=32, 3-buffer depth-2 counted-vmcnt (r6) ----------
// EPI==0: QKV epilogue, fused RoPE for q/k; v via LDS-transpose -> coalesced 16B stores.
// EPI==1: fp32 out.
template <int EPI, int NX>
__global__ __launch_bounds__(256) void gemm_nt(const u16* __restrict__ A, const u16* __restrict__ Bw,
                                               u16* __restrict__ o0, u16* __restrict__ o1,
                                               u16* __restrict__ o2, float* __restrict__ fo,
                                               const float4* __restrict__ tab) {
  __shared__ __align__(16) u16 SMEM[24576];   // 48KB: As 3x4096 | Bs 3x4096; v-epi reuses 4x5120
  u16* const Asb = SMEM;
  u16* const Bsb = SMEM + 12288;
  const int tid = threadIdx.x;
  const int w = tid >> 6, l = tid & 63;
  const int wm = w >> 1, wn = w & 1;
  // XCD-aware bijective swizzle: consecutive work-ids share the A row-panel -> same XCD L2
  const int L = blockIdx.y * NX + blockIdx.x;
  const int cpx = (NX * 144) / 8;
  const int W = (L & 7) * cpx + (L >> 3);
  const int by = W / NX, bx = W - by * NX;
  const int m0 = by * 128, n0 = bx * 128;
  const int lr = l & 15, lg = l >> 4;
  const int srow = l >> 2;        // 0..15
  const int skk = (l & 3) * 8;    // 0,8,16,24
  f32x4 acc[4][4] = {};

#define COMPUTE(buf)                                                                        \
  {                                                                                         \
    short8 af[4], bfr[4];                                                                   \
    _Pragma("unroll") for (int mi = 0; mi < 4; ++mi)                                        \
        af[mi] = *(const short8*)(&Asb[(buf) * 4096 + (wm * 64 + mi * 16 + lr) * 32 + lg * 8]);  \
    _Pragma("unroll") for (int ni = 0; ni < 4; ++ni)                                        \
        bfr[ni] = *(const short8*)(&Bsb[(buf) * 4096 + (wn * 64 + ni * 16 + lr) * 32 + lg * 8]); \
    __builtin_amdgcn_s_setprio(1);                                                          \
    _Pragma("unroll") for (int mi = 0; mi < 4; ++mi)                                        \
        _Pragma("unroll") for (int ni = 0; ni < 4; ++ni)                                    \
            acc[mi][ni] = __builtin_amdgcn_mfma_f32_16x16x32_bf16(af[mi], bfr[ni],          \
                                                                  acc[mi][ni], 0, 0, 0);    \
    __builtin_amdgcn_s_setprio(0);                                                          \
  }

  // prologue: stage tiles 0,1 (8 loads); wait until <=4 outstanding -> tile 0 landed
  stage_ab(A, Bw, m0, n0, 0,  Asb, Bsb, w, srow, skk);
  stage_ab(A, Bw, m0, n0, 32, Asb + 4096, Bsb + 4096, w, srow, skk);
  WAITBAR(4)

  int ic = 0;  // buf of tile t (t%3)
  for (int t = 0; t < 30; ++t) {
    int in2 = ic + 2; if (in2 >= 3) in2 -= 3;   // buf of tile t+2
    stage_ab(A, Bw, m0, n0, (t + 2) * 32, Asb + in2 * 4096, Bsb + in2 * 4096, w, srow, skk);
    COMPUTE(ic);
    WAITBAR(4)   // tile t+1's loads (oldest 4) retired; tile t+2's stay in flight
    ++ic; if (ic == 3) ic = 0;
  }
  COMPUTE(0);   // tile 30 (30%3=0)
  WAITBAR(0)    // tile 31 landed for all waves
  COMPUTE(1);   // tile 31 (31%3=1)
#undef COMPUTE

  if (EPI == 0) {
    const float qs = 0.125f * 1.44269504f;  // 1/sqrt(HD) * log2(e), consumed by attn's exp2
    const int nbase = n0 + wn * 64;         // wave-uniform; v-ness is block-uniform (bx 10,11)
    if (nbase >= 1280) {
      // ---- v: LDS transpose -> coalesced [B,G,64,T] stores ----
      const int g = (nbase - 1280) >> 6;
      const int brow = m0 + wm * 64;          // 64-aligned; 576%64==0 -> never crosses batch
      const int bb = brow / T_, t0 = brow - bb * T_;
      u16* tb = SMEM + w * 5120;              // 64 d-rows x stride 80 (4-way max conflict)
      __syncthreads();                        // all K-loop LDS reads done; safe to overwrite
#pragma unroll
      for (int mi = 0; mi < 4; ++mi)
#pragma unroll
        for (int ni = 0; ni < 4; ++ni) {
          u64 pk = (u64)f2bf(acc[mi][ni][0]) | ((u64)f2bf(acc[mi][ni][1]) << 16) |
                   ((u64)f2bf(acc[mi][ni][2]) << 32) | ((u64)f2bf(acc[mi][ni][3]) << 48);
          *(u64*)(tb + (ni * 16 + lr) * 80 + mi * 16 + lg * 4) = pk;
        }
      __syncthreads();                        // publish + order ds write->read
      u16* dst = o2 + ((size_t)(bb * G_ + g) * 64 + l) * T_ + t0;
      const u16* src = tb + l * 80;
#pragma unroll
      for (int j = 0; j < 8; ++j)
        *(short8*)(dst + j * 8) = *(const short8*)(src + j * 8);
    } else {
      // ---- q/k: fused 2D-RoPE in fp32; for fixed (mi,r), ni=0..3 hold d,d+16,d+32,d+48 ----
#pragma unroll
      for (int mi = 0; mi < 4; ++mi) {
#pragma unroll
        for (int r = 0; r < 4; ++r) {
          int mg = m0 + wm * 64 + mi * 16 + lg * 4 + r;
          int bb = mg / T_, t = mg - bb * T_;
          float v0 = acc[mi][0][r], v1 = acc[mi][1][r], v2 = acc[mi][2][r], v3 = acc[mi][3][r];
          float4 tb = tab[t * FD + lr];  // sx cx sy cy
          float sc = (nbase < 1024) ? qs : 1.0f;
          float e0 = (v0 * tb.y - v1 * tb.x) * sc;
          float e1 = (v0 * tb.x + v1 * tb.y) * sc;
          float e2 = (v2 * tb.w - v3 * tb.z) * sc;
          float e3 = (v2 * tb.z + v3 * tb.w) * sc;
          u16* dst;
          if (nbase < 1024) {
            int h = nbase >> 6;
            dst = o0 + (((size_t)bb * H_ + h) * T_ + t) * 64 + lr;
          } else {
            int g = (nbase - 1024) >> 6;
            dst = o1 + (((size_t)bb * G_ + g) * T_ + t) * 64 + lr;
          }
          dst[0] = f2bf(e0); dst[16] = f2bf(e1); dst[32] = f2bf(e2); dst[48] = f2bf(e3);
        }
      }
    }
  } else {
#pragma unroll
    for (int mi = 0; mi < 4; ++mi)
#pragma unroll
      for (int ni = 0; ni < 4; ++ni)
#pragma unroll
        for (int r = 0; r < 4; ++r) {
          int mg = m0 + wm * 64 + mi * 16 + lg * 4 + r;
          int ng = n0 + wn * 64 + ni * 16 + lr;
          fo[(size_t)mg * 1024 + ng] = acc[mi][ni][r];
        }
  }
}

// ---------------- flash attention: r15 structure, swizzled pad-free Pl (LDS 40960 -> 4 blocks/CU)
// Pl element (row,col) stored at row*64 + ((col>>3) ^ (row&7))*8 + (col&7): same XOR on write
// (row = lg*4+r) and read (row = lr) -> bijective per row, values identical to r15's padded
// layout. Kills the 8-way P-read bank conflict and drops LDS below the 4-block threshold.
__device__ __forceinline__ void stage_kv(const u16* __restrict__ k, const u16* __restrict__ vt,
                                         size_t kvbase, int kt, u16* Ksb, u16* Vsb,
                                         int w, int srow, int sblk) {
#pragma unroll
  for (int ii = 0; ii < 2; ++ii) {
    int i = w * 2 + ii;
    int row = i * 8 + srow;
    gl_lds16(k + kvbase + (size_t)(kt * 64 + row) * 64 + sblk * 8, Ksb + i * 512);
    gl_lds16(vt + kvbase + (size_t)row * T_ + kt * 64 + sblk * 8, Vsb + i * 512);
  }
}

__global__ __launch_bounds__(256) void attn_kernel(const u16* __restrict__ q, const u16* __restrict__ k,
                                                   const u16* __restrict__ vt, u16* __restrict__ o) {
  __shared__ __align__(16) u16 Ks[2][64 * 64];
  __shared__ __align__(16) u16 Vs[2][64 * 64];
  __shared__ __align__(16) u16 Pl[4][16 * 64];   // 40960 B total -> exactly 4 blocks/CU
  int L = blockIdx.x;
  int W = (L & 7) * 576 + (L >> 3);
  int qt = W % 9;
  int bh = W / 9;
  int h = bh & 15, b = bh >> 4;
  int g = h >> 2;
  int tid = threadIdx.x;
  int w = tid >> 6, l = tid & 63;
  int lr = l & 15, lg = l >> 4;
  const size_t kvbase = ((size_t)(b * G_ + g)) * (T_ * 64);

  const u16* qptr = q + (((size_t)(b * H_ + h)) * T_ + qt * 64 + w * 16 + lr) * 64;
  short8 qf0 = *(const short8*)(qptr + lg * 8);
  short8 qf1 = *(const short8*)(qptr + 32 + lg * 8);

  float ls[4] = {0.f, 0.f, 0.f, 0.f};
  f32x4 oacc[4];
#pragma unroll
  for (int dt = 0; dt < 4; ++dt) oacc[dt] = (f32x4){0.f, 0.f, 0.f, 0.f};

  const int srow = l >> 3;                 // 0..7
  const int sblk = (l & 7) ^ (srow & 7);   // pre-swizzled source block

  stage_kv(k, vt, kvbase, 0, &Ks[0][0], &Vs[0][0], w, srow, sblk);
  WAITBAR(0)

  int cur = 0;
  for (int kt = 0; kt < 9; ++kt) {
    if (kt < 8)
      stage_kv(k, vt, kvbase, kt + 1, &Ks[cur ^ 1][0], &Vs[cur ^ 1][0], w, srow, sblk);

    f32x4 sacc[4];
#pragma unroll
    for (int ct = 0; ct < 4; ++ct) {
      sacc[ct] = (f32x4){0.f, 0.f, 0.f, 0.f};
      int row = ct * 16 + lr;
      int i0 = (0 * 4 + lg) ^ (row & 7);
      int i1 = (1 * 4 + lg) ^ (row & 7);
      short8 kf0 = *(const short8*)(&Ks[cur][row * 64 + i0 * 8]);
      short8 kf1 = *(const short8*)(&Ks[cur][row * 64 + i1 * 8]);
      sacc[ct] = __builtin_amdgcn_mfma_f32_16x16x32_bf16(qf0, kf0, sacc[ct], 0, 0, 0);
      sacc[ct] = __builtin_amdgcn_mfma_f32_16x16x32_bf16(qf1, kf1, sacc[ct], 0, 0, 0);
    }

    float p[4][4];
#pragma unroll
    for (int ct = 0; ct < 4; ++ct)
#pragma unroll
      for (int r = 0; r < 4; ++r) p[ct][r] = exp2v(sacc[ct][r]);
#pragma unroll
    for (int r = 0; r < 4; ++r) ls[r] += (p[0][r] + p[1][r]) + (p[2][r] + p[3][r]);

    // P -> LDS (swizzled pad-free layout), then PV
    u16* pl = &Pl[w][0];
#pragma unroll
    for (int ct = 0; ct < 4; ++ct)
#pragma unroll
      for (int r = 0; r < 4; ++r) {
        int prow = lg * 4 + r;
        int pblk = (ct * 2 + (lr >> 3)) ^ (prow & 7);
        pl[prow * 64 + pblk * 8 + (lr & 7)] = (u16)((__float_as_uint(p[ct][r]) + 0x8000u) >> 16);
      }
    __builtin_amdgcn_sched_barrier(0);
    asm volatile("s_waitcnt lgkmcnt(0)" ::: "memory");
    __builtin_amdgcn_sched_barrier(0);
#pragma unroll
    for (int c = 0; c < 2; ++c) {
      int rblk = (c * 4 + lg) ^ (lr & 7);
      short8 pf = *(const short8*)(pl + lr * 64 + rblk * 8);
#pragma unroll
      for (int dt = 0; dt < 4; ++dt) {
        int row = dt * 16 + lr;
        int blk = (c * 4 + lg) ^ (row & 7);
        short8 vf = *(const short8*)(&Vs[cur][row * 64 + blk * 8]);
        oacc[dt] = __builtin_amdgcn_mfma_f32_16x16x32_bf16(pf, vf, oacc[dt], 0, 0, 0);
      }
    }

    if (kt < 8) {
      WAITBAR(0)
      cur ^= 1;
    }
  }

#pragma unroll
  for (int mk = 1; mk <= 8; mk <<= 1)
#pragma unroll
    for (int r = 0; r < 4; ++r) ls[r] += __shfl_xor(ls[r], mk);

#pragma unroll
  for (int dt = 0; dt < 4; ++dt)
#pragma unroll
    for (int r = 0; r < 4; ++r) {
      int trow = qt * 64 + w * 16 + lg * 4 + r;
      float v = oacc[dt][r] / ls[r];
      o[((size_t)b * T_ + trow) * 1024 + h * 64 + dt * 16 + lr] = f2bf(v);
    }
}

extern "C" void kernel_launch(void* const* d_in, const int* in_sizes, int n_in,
                              void* d_out, int out_size, void* d_ws, size_t ws_size,
                              hipStream_t stream) {
  const float* x = (const float*)d_in[0];
  const float* wqkv = (const float*)d_in[1];
  const float* wo = (const float*)d_in[2];
  float* out = (float*)d_out;

  u16* ws = (u16*)d_ws;
  u16* xb = ws;                                  // reused as attn-out
  u16* wqkvb = xb + (size_t)BT * DM;
  u16* wob = wqkvb + (size_t)NQKV * DM;
  u16* qb = wob + (size_t)DM * DM;
  u16* kb = qb + (size_t)BT * DM;
  u16* vtb = kb + (size_t)B_ * G_ * T_ * 64;
  float4* tab = (float4*)(vtb + (size_t)B_ * G_ * T_ * 64);
  u16* ob = xb;  // alias: x-bf16 is dead after gemm<0>

  const int prep_items = NX4 + NQ4 + NW4 + T_ * FD;
  prep_kernel<<<(prep_items + 255) / 256, 256, 0, stream>>>(
      (const float4*)x, (const float4*)wqkv, (const float4*)wo, xb, wqkvb, wob, tab);
  gemm_nt<0, 12><<<dim3(12, 144), 256, 0, stream>>>(xb, wqkvb, qb, kb, vtb, nullptr, tab);
  attn_kernel<<<B_ * H_ * 9, 256, 0, stream>>>(qb, kb, vtb, ob);
  gemm_nt<1, 8><<<dim3(8, 144), 256, 0, stream>>>(ob, wob, nullptr, nullptr, nullptr, out, nullptr);
}

// Round 17
// 244.503 us; speedup vs baseline: 1.0290x; 1.0290x over previous
//
#include <hip/hip_runtime.h>

typedef unsigned short u16;
typedef unsigned long long u64;
typedef __attribute__((ext_vector_type(8))) short short8;
typedef __attribute__((ext_vector_type(4))) float f32x4;

#define B_ 32
#define T_ 576
#define H_ 16
#define G_ 4
#define HD_ 64
#define DM 1024
#define NQKV 1536
#define BT (B_*T_)
#define GRID2D 24
#define FD 16

__device__ __forceinline__ u16 f2bf(float f) {
  unsigned u = __float_as_uint(f);
  u = (u + 0x7FFFu + ((u >> 16) & 1u)) >> 16;
  return (u16)u;
}
__device__ __forceinline__ float exp2v(float x) {
  float r;
  asm("v_exp_f32 %0, %1" : "=v"(r) : "v"(x));
  return r;
}

__device__ __forceinline__ void gl_lds16(const u16* g, u16* lds) {
  __builtin_amdgcn_global_load_lds((const __attribute__((address_space(1))) unsigned int*)g,
                                   (__attribute__((address_space(3))) unsigned int*)lds, 16, 0, 0);
}

// fenced wait: nothing may be scheduled across the waitcnt+barrier (rule #18 / r4-vs-r6 A/B)
#define WAITBAR(N)                                        \
  __builtin_amdgcn_sched_barrier(0);                      \
  asm volatile("s_waitcnt vmcnt(" #N ")\n\ts_barrier" ::: "memory"); \
  __builtin_amdgcn_sched_barrier(0);

// ---------------- fused prep: fp32->bf16 (x, w_qkv, w_o) + RoPE table, one launch ----------------
__device__ __forceinline__ void cvt4(const float4* __restrict__ in, u16* __restrict__ o, int i) {
  float4 v = in[i];
  u64 pk = (u64)f2bf(v.x) | ((u64)f2bf(v.y) << 16) | ((u64)f2bf(v.z) << 32) | ((u64)f2bf(v.w) << 48);
  *(u64*)(o + (size_t)i * 4) = pk;
}

#define NX4 (BT*DM/4)
#define NQ4 (NQKV*DM/4)
#define NW4 (DM*DM/4)

__global__ __launch_bounds__(256) void prep_kernel(const float4* __restrict__ x, const float4* __restrict__ wq,
                                                   const float4* __restrict__ wo,
                                                   u16* __restrict__ xb, u16* __restrict__ wqb,
                                                   u16* __restrict__ wob, float4* __restrict__ tab) {
  int i = blockIdx.x * 256 + threadIdx.x;
  if (i < NX4) { cvt4(x, xb, i); return; }
  i -= NX4;
  if (i < NQ4) { cvt4(wq, wqb, i); return; }
  i -= NQ4;
  if (i < NW4) { cvt4(wo, wob, i); return; }
  i -= NW4;
  if (i >= T_ * FD) return;
  int t = i >> 4, j = i & 15;
  float inv = powf(10000.0f, -(float)j / 16.0f);
  float tx = (float)(t / GRID2D) * inv;
  float ty = (float)(t % GRID2D) * inv;
  float4 r;
  r.x = sinf(tx); r.y = cosf(tx); r.z = sinf(ty); r.w = cosf(ty);
  tab[i] = r;
}

// ---------------- staging helper ----------------
__device__ __forceinline__ void stage_ab(const u16* __restrict__ A, const u16* __restrict__ Bw,
                                         int m0, int n0, int k0, u16* Asb, u16* Bsb,
                                         int w, int srow, int skk) {
#pragma unroll
  for (int ii = 0; ii < 2; ++ii) {
    int i = w * 2 + ii;
    int row = i * 16 + srow;
    gl_lds16(A + (size_t)(m0 + row) * DM + k0 + skk, Asb + i * 512);
    gl_lds16(Bw + (size_t)(n0 + row) * DM + k0 + skk, Bsb + i * 512);
  }
}

// ---------------- bf16 NT GEMM, 128x128 tile, BK=32, 3-buffer depth-2 counted-vmcnt (r6) ----------
// EPI==0: QKV epilogue, fused RoPE for q/k; v via LDS-transpose -> coalesced 16B stores.
// EPI==1: fp32 out.
template <int EPI, int NX>
__global__ __launch_bounds__(256) void gemm_nt(const u16* __restrict__ A, const u16* __restrict__ Bw,
                                               u16* __restrict__ o0, u16* __restrict__ o1,
                                               u16* __restrict__ o2, float* __restrict__ fo,
                                               const float4* __restrict__ tab) {
  __shared__ __align__(16) u16 SMEM[24576];   // 48KB: As 3x4096 | Bs 3x4096; v-epi reuses 4x5120
  u16* const Asb = SMEM;
  u16* const Bsb = SMEM + 12288;
  const int tid = threadIdx.x;
  const int w = tid >> 6, l = tid & 63;
  const int wm = w >> 1, wn = w & 1;
  // XCD-aware bijective swizzle: consecutive work-ids share the A row-panel -> same XCD L2
  const int L = blockIdx.y * NX + blockIdx.x;
  const int cpx = (NX * 144) / 8;
  const int W = (L & 7) * cpx + (L >> 3);
  const int by = W / NX, bx = W - by * NX;
  const int m0 = by * 128, n0 = bx * 128;
  const int lr = l & 15, lg = l >> 4;
  const int srow = l >> 2;        // 0..15
  const int skk = (l & 3) * 8;    // 0,8,16,24
  f32x4 acc[4][4] = {};

#define COMPUTE(buf)                                                                        \
  {                                                                                         \
    short8 af[4], bfr[4];                                                                   \
    _Pragma("unroll") for (int mi = 0; mi < 4; ++mi)                                        \
        af[mi] = *(const short8*)(&Asb[(buf) * 4096 + (wm * 64 + mi * 16 + lr) * 32 + lg * 8]);  \
    _Pragma("unroll") for (int ni = 0; ni < 4; ++ni)                                        \
        bfr[ni] = *(const short8*)(&Bsb[(buf) * 4096 + (wn * 64 + ni * 16 + lr) * 32 + lg * 8]); \
    __builtin_amdgcn_s_setprio(1);                                                          \
    _Pragma("unroll") for (int mi = 0; mi < 4; ++mi)                                        \
        _Pragma("unroll") for (int ni = 0; ni < 4; ++ni)                                    \
            acc[mi][ni] = __builtin_amdgcn_mfma_f32_16x16x32_bf16(af[mi], bfr[ni],          \
                                                                  acc[mi][ni], 0, 0, 0);    \
    __builtin_amdgcn_s_setprio(0);                                                          \
  }

  // prologue: stage tiles 0,1 (8 loads); wait until <=4 outstanding -> tile 0 landed
  stage_ab(A, Bw, m0, n0, 0,  Asb, Bsb, w, srow, skk);
  stage_ab(A, Bw, m0, n0, 32, Asb + 4096, Bsb + 4096, w, srow, skk);
  WAITBAR(4)

  int ic = 0;  // buf of tile t (t%3)
  for (int t = 0; t < 30; ++t) {
    int in2 = ic + 2; if (in2 >= 3) in2 -= 3;   // buf of tile t+2
    stage_ab(A, Bw, m0, n0, (t + 2) * 32, Asb + in2 * 4096, Bsb + in2 * 4096, w, srow, skk);
    COMPUTE(ic);
    WAITBAR(4)   // tile t+1's loads (oldest 4) retired; tile t+2's stay in flight
    ++ic; if (ic == 3) ic = 0;
  }
  COMPUTE(0);   // tile 30 (30%3=0)
  WAITBAR(0)    // tile 31 landed for all waves
  COMPUTE(1);   // tile 31 (31%3=1)
#undef COMPUTE

  if (EPI == 0) {
    const float qs = 0.125f * 1.44269504f;  // 1/sqrt(HD) * log2(e), consumed by attn's exp2
    const int nbase = n0 + wn * 64;         // wave-uniform; v-ness is block-uniform (bx 10,11)
    if (nbase >= 1280) {
      // ---- v: LDS transpose -> coalesced [B,G,64,T] stores ----
      const int g = (nbase - 1280) >> 6;
      const int brow = m0 + wm * 64;          // 64-aligned; 576%64==0 -> never crosses batch
      const int bb = brow / T_, t0 = brow - bb * T_;
      u16* tb = SMEM + w * 5120;              // 64 d-rows x stride 80 (4-way max conflict)
      __syncthreads();                        // all K-loop LDS reads done; safe to overwrite
#pragma unroll
      for (int mi = 0; mi < 4; ++mi)
#pragma unroll
        for (int ni = 0; ni < 4; ++ni) {
          u64 pk = (u64)f2bf(acc[mi][ni][0]) | ((u64)f2bf(acc[mi][ni][1]) << 16) |
                   ((u64)f2bf(acc[mi][ni][2]) << 32) | ((u64)f2bf(acc[mi][ni][3]) << 48);
          *(u64*)(tb + (ni * 16 + lr) * 80 + mi * 16 + lg * 4) = pk;
        }
      __syncthreads();                        // publish + order ds write->read
      u16* dst = o2 + ((size_t)(bb * G_ + g) * 64 + l) * T_ + t0;
      const u16* src = tb + l * 80;
#pragma unroll
      for (int j = 0; j < 8; ++j)
        *(short8*)(dst + j * 8) = *(const short8*)(src + j * 8);
    } else {
      // ---- q/k: fused 2D-RoPE in fp32; for fixed (mi,r), ni=0..3 hold d,d+16,d+32,d+48 ----
#pragma unroll
      for (int mi = 0; mi < 4; ++mi) {
#pragma unroll
        for (int r = 0; r < 4; ++r) {
          int mg = m0 + wm * 64 + mi * 16 + lg * 4 + r;
          int bb = mg / T_, t = mg - bb * T_;
          float v0 = acc[mi][0][r], v1 = acc[mi][1][r], v2 = acc[mi][2][r], v3 = acc[mi][3][r];
          float4 tb = tab[t * FD + lr];  // sx cx sy cy
          float sc = (nbase < 1024) ? qs : 1.0f;
          float e0 = (v0 * tb.y - v1 * tb.x) * sc;
          float e1 = (v0 * tb.x + v1 * tb.y) * sc;
          float e2 = (v2 * tb.w - v3 * tb.z) * sc;
          float e3 = (v2 * tb.z + v3 * tb.w) * sc;
          u16* dst;
          if (nbase < 1024) {
            int h = nbase >> 6;
            dst = o0 + (((size_t)bb * H_ + h) * T_ + t) * 64 + lr;
          } else {
            int g = (nbase - 1024) >> 6;
            dst = o1 + (((size_t)bb * G_ + g) * T_ + t) * 64 + lr;
          }
          dst[0] = f2bf(e0); dst[16] = f2bf(e1); dst[32] = f2bf(e2); dst[48] = f2bf(e3);
        }
      }
    }
  } else {
#pragma unroll
    for (int mi = 0; mi < 4; ++mi)
#pragma unroll
      for (int ni = 0; ni < 4; ++ni)
#pragma unroll
        for (int r = 0; r < 4; ++r) {
          int mg = m0 + wm * 64 + mi * 16 + lg * 4 + r;
          int ng = n0 + wn * 64 + ni * 16 + lr;
          fo[(size_t)mg * 1024 + ng] = acc[mi][ni][r];
        }
  }
}

// ---------------- flash attention: 32 q-rows/wave, K/V fragments amortized over 2 sub-bodies ---
// Block = (b, h, qt in 0..4) covering 128 q-rows (qt=4: only sub-A's 64 valid). Per tile each
// wave runs the r16-verified body twice (sub A: rows +w*16, sub B: rows +64+w*16) sharing ONE
// kf/vf LDS read -> b128 reads per 32 rows drop 40->20 (the LDS pipe was the measured bound).
__device__ __forceinline__ void stage_kv(const u16* __restrict__ k, const u16* __restrict__ vt,
                                         size_t kvbase, int kt, u16* Ksb, u16* Vsb,
                                         int w, int srow, int sblk) {
#pragma unroll
  for (int ii = 0; ii < 2; ++ii) {
    int i = w * 2 + ii;
    int row = i * 8 + srow;
    gl_lds16(k + kvbase + (size_t)(kt * 64 + row) * 64 + sblk * 8, Ksb + i * 512);
    gl_lds16(vt + kvbase + (size_t)row * T_ + kt * 64 + sblk * 8, Vsb + i * 512);
  }
}

__global__ __launch_bounds__(256) void attn_kernel(const u16* __restrict__ q, const u16* __restrict__ k,
                                                   const u16* __restrict__ vt, u16* __restrict__ o) {
  __shared__ __align__(16) u16 Ks[2][64 * 64];
  __shared__ __align__(16) u16 Vs[2][64 * 64];
  __shared__ __align__(16) u16 Pl[4][2][16 * 64];   // per wave, per sub; 49152 B -> 3 blocks/CU
  int L = blockIdx.x;                                // 2560 blocks (2560 % 8 == 0)
  int W = (L & 7) * 320 + (L >> 3);
  int qt = W % 5;
  int bh = W / 5;
  int h = bh & 15, b = bh >> 4;
  int g = h >> 2;
  int tid = threadIdx.x;
  int w = tid >> 6, l = tid & 63;
  int lr = l & 15, lg = l >> 4;
  const size_t kvbase = ((size_t)(b * G_ + g)) * (T_ * 64);

  const bool okB = (qt < 4);                 // qt==4: rows 512..575 only (sub-A)
  const int qrA = qt * 128 + w * 16;
  const int qrB = okB ? (qrA + 64) : qrA;    // clamped (valid memory; results unstored)
  const u16* qpA = q + (((size_t)(b * H_ + h)) * T_ + qrA + lr) * 64;
  const u16* qpB = q + (((size_t)(b * H_ + h)) * T_ + qrB + lr) * 64;
  short8 qfA0 = *(const short8*)(qpA + lg * 8);
  short8 qfA1 = *(const short8*)(qpA + 32 + lg * 8);
  short8 qfB0 = *(const short8*)(qpB + lg * 8);
  short8 qfB1 = *(const short8*)(qpB + 32 + lg * 8);

  float lsA[4] = {0.f, 0.f, 0.f, 0.f}, lsB[4] = {0.f, 0.f, 0.f, 0.f};
  f32x4 oaccA[4], oaccB[4];
#pragma unroll
  for (int dt = 0; dt < 4; ++dt) {
    oaccA[dt] = (f32x4){0.f, 0.f, 0.f, 0.f};
    oaccB[dt] = (f32x4){0.f, 0.f, 0.f, 0.f};
  }

  const int srow = l >> 3;                 // 0..7
  const int sblk = (l & 7) ^ (srow & 7);   // pre-swizzled source block

  stage_kv(k, vt, kvbase, 0, &Ks[0][0], &Vs[0][0], w, srow, sblk);
  WAITBAR(0)

  int cur = 0;
  for (int kt = 0; kt < 9; ++kt) {
    if (kt < 8)
      stage_kv(k, vt, kvbase, kt + 1, &Ks[cur ^ 1][0], &Vs[cur ^ 1][0], w, srow, sblk);

    // QK^T for both subs; kf loaded ONCE per ct
    f32x4 sA[4], sB[4];
#pragma unroll
    for (int ct = 0; ct < 4; ++ct) {
      sA[ct] = (f32x4){0.f, 0.f, 0.f, 0.f};
      sB[ct] = (f32x4){0.f, 0.f, 0.f, 0.f};
      int row = ct * 16 + lr;
      int i0 = (0 * 4 + lg) ^ (row & 7);
      int i1 = (1 * 4 + lg) ^ (row & 7);
      short8 kf0 = *(const short8*)(&Ks[cur][row * 64 + i0 * 8]);
      short8 kf1 = *(const short8*)(&Ks[cur][row * 64 + i1 * 8]);
      sA[ct] = __builtin_amdgcn_mfma_f32_16x16x32_bf16(qfA0, kf0, sA[ct], 0, 0, 0);
      sA[ct] = __builtin_amdgcn_mfma_f32_16x16x32_bf16(qfA1, kf1, sA[ct], 0, 0, 0);
      sB[ct] = __builtin_amdgcn_mfma_f32_16x16x32_bf16(qfB0, kf0, sB[ct], 0, 0, 0);
      sB[ct] = __builtin_amdgcn_mfma_f32_16x16x32_bf16(qfB1, kf1, sB[ct], 0, 0, 0);
    }

    // softmax (no-max form) + swizzled P-write, per sub
    u16* plA = &Pl[w][0][0];
    u16* plB = &Pl[w][1][0];
#pragma unroll
    for (int ct = 0; ct < 4; ++ct) {
      float pA[4], pB[4];
#pragma unroll
      for (int r = 0; r < 4; ++r) { pA[r] = exp2v(sA[ct][r]); pB[r] = exp2v(sB[ct][r]); }
#pragma unroll
      for (int r = 0; r < 4; ++r) { lsA[r] += pA[r]; lsB[r] += pB[r]; }
#pragma unroll
      for (int r = 0; r < 4; ++r) {
        int prow = lg * 4 + r;
        int pblk = (ct * 2 + (lr >> 3)) ^ (prow & 7);
        int off = prow * 64 + pblk * 8 + (lr & 7);
        plA[off] = (u16)((__float_as_uint(pA[r]) + 0x8000u) >> 16);
        plB[off] = (u16)((__float_as_uint(pB[r]) + 0x8000u) >> 16);
      }
    }
    __builtin_amdgcn_sched_barrier(0);
    asm volatile("s_waitcnt lgkmcnt(0)" ::: "memory");
    __builtin_amdgcn_sched_barrier(0);

    // PV for both subs; vf loaded ONCE per (c,dt)
#pragma unroll
    for (int c = 0; c < 2; ++c) {
      int rblk = (c * 4 + lg) ^ (lr & 7);
      short8 pfA = *(const short8*)(plA + lr * 64 + rblk * 8);
      short8 pfB = *(const short8*)(plB + lr * 64 + rblk * 8);
#pragma unroll
      for (int dt = 0; dt < 4; ++dt) {
        int row = dt * 16 + lr;
        int blk = (c * 4 + lg) ^ (row & 7);
        short8 vf = *(const short8*)(&Vs[cur][row * 64 + blk * 8]);
        oaccA[dt] = __builtin_amdgcn_mfma_f32_16x16x32_bf16(pfA, vf, oaccA[dt], 0, 0, 0);
        oaccB[dt] = __builtin_amdgcn_mfma_f32_16x16x32_bf16(pfB, vf, oaccB[dt], 0, 0, 0);
      }
    }

    if (kt < 8) {
      WAITBAR(0)
      cur ^= 1;
    }
  }

  // final row-sum reduces (wave-local), per sub
#pragma unroll
  for (int mk = 1; mk <= 8; mk <<= 1)
#pragma unroll
    for (int r = 0; r < 4; ++r) { lsA[r] += __shfl_xor(lsA[r], mk); lsB[r] += __shfl_xor(lsB[r], mk); }

  // normalize + store attn-out [B,T,H*HD] bf16
#pragma unroll
  for (int dt = 0; dt < 4; ++dt)
#pragma unroll
    for (int r = 0; r < 4; ++r) {
      int trowA = qt * 128 + w * 16 + lg * 4 + r;
      float vA = oaccA[dt][r] / lsA[r];
      o[((size_t)b * T_ + trowA) * 1024 + h * 64 + dt * 16 + lr] = f2bf(vA);
    }
  if (okB) {
#pragma unroll
    for (int dt = 0; dt < 4; ++dt)
#pragma unroll
      for (int r = 0; r < 4; ++r) {
        int trowB = qt * 128 + 64 + w * 16 + lg * 4 + r;
        float vB = oaccB[dt][r] / lsB[r];
        o[((size_t)b * T_ + trowB) * 1024 + h * 64 + dt * 16 + lr] = f2bf(vB);
      }
  }
}

extern "C" void kernel_launch(void* const* d_in, const int* in_sizes, int n_in,
                              void* d_out, int out_size, void* d_ws, size_t ws_size,
                              hipStream_t stream) {
  const float* x = (const float*)d_in[0];
  const float* wqkv = (const float*)d_in[1];
  const float* wo = (const float*)d_in[2];
  float* out = (float*)d_out;

  u16* ws = (u16*)d_ws;
  u16* xb = ws;                                  // reused as attn-out
  u16* wqkvb = xb + (size_t)BT * DM;
  u16* wob = wqkvb + (size_t)NQKV * DM;
  u16* qb = wob + (size_t)DM * DM;
  u16* kb = qb + (size_t)BT * DM;
  u16* vtb = kb + (size_t)B_ * G_ * T_ * 64;
  float4* tab = (float4*)(vtb + (size_t)B_ * G_ * T_ * 64);
  u16* ob = xb;  // alias: x-bf16 is dead after gemm<0>

  const int prep_items = NX4 + NQ4 + NW4 + T_ * FD;
  prep_kernel<<<(prep_items + 255) / 256, 256, 0, stream>>>(
      (const float4*)x, (const float4*)wqkv, (const float4*)wo, xb, wqkvb, wob, tab);
  gemm_nt<0, 12><<<dim3(12, 144), 256, 0, stream>>>(xb, wqkvb, qb, kb, vtb, nullptr, tab);
  attn_kernel<<<B_ * H_ * 5, 256, 0, stream>>>(qb, kb, vtb, ob);
  gemm_nt<1, 8><<<dim3(8, 144), 256, 0, stream>>>(ob, wob, nullptr, nullptr, nullptr, out, nullptr);
}

// Round 19
// 241.785 us; speedup vs baseline: 1.0406x; 1.0112x over previous
//
#include <hip/hip_runtime.h>

typedef unsigned short u16;
typedef unsigned long long u64;
typedef __attribute__((ext_vector_type(8))) short short8;
typedef __attribute__((ext_vector_type(4))) float f32x4;

#define B_ 32
#define T_ 576
#define H_ 16
#define G_ 4
#define HD_ 64
#define DM 1024
#define NQKV 1536
#define BT (B_*T_)
#define GRID2D 24
#define FD 16

__device__ __forceinline__ u16 f2bf(float f) {
  unsigned u = __float_as_uint(f);
  u = (u + 0x7FFFu + ((u >> 16) & 1u)) >> 16;
  return (u16)u;
}
__device__ __forceinline__ float exp2v(float x) {
  float r;
  asm("v_exp_f32 %0, %1" : "=v"(r) : "v"(x));
  return r;
}

__device__ __forceinline__ void gl_lds16(const u16* g, u16* lds) {
  __builtin_amdgcn_global_load_lds((const __attribute__((address_space(1))) unsigned int*)g,
                                   (__attribute__((address_space(3))) unsigned int*)lds, 16, 0, 0);
}

// fenced wait: nothing may be scheduled across the waitcnt+barrier (rule #18 / r4-vs-r6 A/B)
#define WAITBAR(N)                                        \
  __builtin_amdgcn_sched_barrier(0);                      \
  asm volatile("s_waitcnt vmcnt(" #N ")\n\ts_barrier" ::: "memory"); \
  __builtin_amdgcn_sched_barrier(0);

// ---------------- fused prep: fp32->bf16 (x, w_qkv, w_o) + RoPE table, one launch ----------------
__device__ __forceinline__ void cvt4(const float4* __restrict__ in, u16* __restrict__ o, int i) {
  float4 v = in[i];
  u64 pk = (u64)f2bf(v.x) | ((u64)f2bf(v.y) << 16) | ((u64)f2bf(v.z) << 32) | ((u64)f2bf(v.w) << 48);
  *(u64*)(o + (size_t)i * 4) = pk;
}

#define NX4 (BT*DM/4)
#define NQ4 (NQKV*DM/4)
#define NW4 (DM*DM/4)

__global__ __launch_bounds__(256) void prep_kernel(const float4* __restrict__ x, const float4* __restrict__ wq,
                                                   const float4* __restrict__ wo,
                                                   u16* __restrict__ xb, u16* __restrict__ wqb,
                                                   u16* __restrict__ wob, float4* __restrict__ tab) {
  int i = blockIdx.x * 256 + threadIdx.x;
  if (i < NX4) { cvt4(x, xb, i); return; }
  i -= NX4;
  if (i < NQ4) { cvt4(wq, wqb, i); return; }
  i -= NQ4;
  if (i < NW4) { cvt4(wo, wob, i); return; }
  i -= NW4;
  if (i >= T_ * FD) return;
  int t = i >> 4, j = i & 15;
  float inv = powf(10000.0f, -(float)j / 16.0f);
  float tx = (float)(t / GRID2D) * inv;
  float ty = (float)(t % GRID2D) * inv;
  float4 r;
  r.x = sinf(tx); r.y = cosf(tx); r.z = sinf(ty); r.w = cosf(ty);
  tab[i] = r;
}

// ---------------- staging helper ----------------
__device__ __forceinline__ void stage_ab(const u16* __restrict__ A, const u16* __restrict__ Bw,
                                         int m0, int n0, int k0, u16* Asb, u16* Bsb,
                                         int w, int srow, int skk) {
#pragma unroll
  for (int ii = 0; ii < 2; ++ii) {
    int i = w * 2 + ii;
    int row = i * 16 + srow;
    gl_lds16(A + (size_t)(m0 + row) * DM + k0 + skk, Asb + i * 512);
    gl_lds16(Bw + (size_t)(n0 + row) * DM + k0 + skk, Bsb + i * 512);
  }
}

// ---------------- bf16 NT GEMM, 128x128 tile, BK=32, 3-buffer depth-2 counted-vmcnt (r6) ----------
// EPI==0: QKV epilogue, fused RoPE for q/k; v via LDS-transpose -> coalesced 16B stores.
// EPI==1: fp32 out.
template <int EPI, int NX>
__global__ __launch_bounds__(256) void gemm_nt(const u16* __restrict__ A, const u16* __restrict__ Bw,
                                               u16* __restrict__ o0, u16* __restrict__ o1,
                                               u16* __restrict__ o2, float* __restrict__ fo,
                                               const float4* __restrict__ tab) {
  __shared__ __align__(16) u16 SMEM[24576];   // 48KB: As 3x4096 | Bs 3x4096; v-epi reuses 4x5120
  u16* const Asb = SMEM;
  u16* const Bsb = SMEM + 12288;
  const int tid = threadIdx.x;
  const int w = tid >> 6, l = tid & 63;
  const int wm = w >> 1, wn = w & 1;
  // XCD-aware bijective swizzle: consecutive work-ids share the A row-panel -> same XCD L2
  const int L = blockIdx.y * NX + blockIdx.x;
  const int cpx = (NX * 144) / 8;
  const int W = (L & 7) * cpx + (L >> 3);
  const int by = W / NX, bx = W - by * NX;
  const int m0 = by * 128, n0 = bx * 128;
  const int lr = l & 15, lg = l >> 4;
  const int srow = l >> 2;        // 0..15
  const int skk = (l & 3) * 8;    // 0,8,16,24
  f32x4 acc[4][4] = {};

#define COMPUTE(buf)                                                                        \
  {                                                                                         \
    short8 af[4], bfr[4];                                                                   \
    _Pragma("unroll") for (int mi = 0; mi < 4; ++mi)                                        \
        af[mi] = *(const short8*)(&Asb[(buf) * 4096 + (wm * 64 + mi * 16 + lr) * 32 + lg * 8]);  \
    _Pragma("unroll") for (int ni = 0; ni < 4; ++ni)                                        \
        bfr[ni] = *(const short8*)(&Bsb[(buf) * 4096 + (wn * 64 + ni * 16 + lr) * 32 + lg * 8]); \
    __builtin_amdgcn_s_setprio(1);                                                          \
    _Pragma("unroll") for (int mi = 0; mi < 4; ++mi)                                        \
        _Pragma("unroll") for (int ni = 0; ni < 4; ++ni)                                    \
            acc[mi][ni] = __builtin_amdgcn_mfma_f32_16x16x32_bf16(af[mi], bfr[ni],          \
                                                                  acc[mi][ni], 0, 0, 0);    \
    __builtin_amdgcn_s_setprio(0);                                                          \
  }

  // prologue: stage tiles 0,1 (8 loads); wait until <=4 outstanding -> tile 0 landed
  stage_ab(A, Bw, m0, n0, 0,  Asb, Bsb, w, srow, skk);
  stage_ab(A, Bw, m0, n0, 32, Asb + 4096, Bsb + 4096, w, srow, skk);
  WAITBAR(4)

  int ic = 0;  // buf of tile t (t%3)
  for (int t = 0; t < 30; ++t) {
    int in2 = ic + 2; if (in2 >= 3) in2 -= 3;   // buf of tile t+2
    stage_ab(A, Bw, m0, n0, (t + 2) * 32, Asb + in2 * 4096, Bsb + in2 * 4096, w, srow, skk);
    COMPUTE(ic);
    WAITBAR(4)   // tile t+1's loads (oldest 4) retired; tile t+2's stay in flight
    ++ic; if (ic == 3) ic = 0;
  }
  COMPUTE(0);   // tile 30 (30%3=0)
  WAITBAR(0)    // tile 31 landed for all waves
  COMPUTE(1);   // tile 31 (31%3=1)
#undef COMPUTE

  if (EPI == 0) {
    const float qs = 0.125f * 1.44269504f;  // 1/sqrt(HD) * log2(e), consumed by attn's exp2
    const int nbase = n0 + wn * 64;         // wave-uniform; v-ness is block-uniform (bx 10,11)
    if (nbase >= 1280) {
      // ---- v: LDS transpose -> coalesced [B,G,64,T] stores ----
      const int g = (nbase - 1280) >> 6;
      const int brow = m0 + wm * 64;          // 64-aligned; 576%64==0 -> never crosses batch
      const int bb = brow / T_, t0 = brow - bb * T_;
      u16* tb = SMEM + w * 5120;              // 64 d-rows x stride 80 (4-way max conflict)
      __syncthreads();                        // all K-loop LDS reads done; safe to overwrite
#pragma unroll
      for (int mi = 0; mi < 4; ++mi)
#pragma unroll
        for (int ni = 0; ni < 4; ++ni) {
          u64 pk = (u64)f2bf(acc[mi][ni][0]) | ((u64)f2bf(acc[mi][ni][1]) << 16) |
                   ((u64)f2bf(acc[mi][ni][2]) << 32) | ((u64)f2bf(acc[mi][ni][3]) << 48);
          *(u64*)(tb + (ni * 16 + lr) * 80 + mi * 16 + lg * 4) = pk;
        }
      __syncthreads();                        // publish + order ds write->read
      u16* dst = o2 + ((size_t)(bb * G_ + g) * 64 + l) * T_ + t0;
      const u16* src = tb + l * 80;
#pragma unroll
      for (int j = 0; j < 8; ++j)
        *(short8*)(dst + j * 8) = *(const short8*)(src + j * 8);
    } else {
      // ---- q/k: fused 2D-RoPE in fp32; for fixed (mi,r), ni=0..3 hold d,d+16,d+32,d+48 ----
#pragma unroll
      for (int mi = 0; mi < 4; ++mi) {
#pragma unroll
        for (int r = 0; r < 4; ++r) {
          int mg = m0 + wm * 64 + mi * 16 + lg * 4 + r;
          int bb = mg / T_, t = mg - bb * T_;
          float v0 = acc[mi][0][r], v1 = acc[mi][1][r], v2 = acc[mi][2][r], v3 = acc[mi][3][r];
          float4 tb = tab[t * FD + lr];  // sx cx sy cy
          float sc = (nbase < 1024) ? qs : 1.0f;
          float e0 = (v0 * tb.y - v1 * tb.x) * sc;
          float e1 = (v0 * tb.x + v1 * tb.y) * sc;
          float e2 = (v2 * tb.w - v3 * tb.z) * sc;
          float e3 = (v2 * tb.z + v3 * tb.w) * sc;
          u16* dst;
          if (nbase < 1024) {
            int h = nbase >> 6;
            dst = o0 + (((size_t)bb * H_ + h) * T_ + t) * 64 + lr;
          } else {
            int g = (nbase - 1024) >> 6;
            dst = o1 + (((size_t)bb * G_ + g) * T_ + t) * 64 + lr;
          }
          dst[0] = f2bf(e0); dst[16] = f2bf(e1); dst[32] = f2bf(e2); dst[48] = f2bf(e3);
        }
      }
    }
  } else {
#pragma unroll
    for (int mi = 0; mi < 4; ++mi)
#pragma unroll
      for (int ni = 0; ni < 4; ++ni)
#pragma unroll
        for (int r = 0; r < 4; ++r) {
          int mg = m0 + wm * 64 + mi * 16 + lg * 4 + r;
          int ng = n0 + wn * 64 + ni * 16 + lr;
          fo[(size_t)mg * 1024 + ng] = acc[mi][ni][r];
        }
  }
}

// ---------------- flash attention: 32 q-rows/wave, K/V fragments amortized over 2 sub-bodies ---
// Block = (b, h, qt in 0..4) covering 128 q-rows (qt=4: only sub-A's 64 valid). Per tile each
// wave runs the r16-verified body twice (sub A: rows +w*16, sub B: rows +64+w*16) sharing ONE
// kf/vf LDS read. 4 waves / 256 threads — the verified envelope (all >4-wave variants failed).
__device__ __forceinline__ void stage_kv(const u16* __restrict__ k, const u16* __restrict__ vt,
                                         size_t kvbase, int kt, u16* Ksb, u16* Vsb,
                                         int w, int srow, int sblk) {
#pragma unroll
  for (int ii = 0; ii < 2; ++ii) {
    int i = w * 2 + ii;
    int row = i * 8 + srow;
    gl_lds16(k + kvbase + (size_t)(kt * 64 + row) * 64 + sblk * 8, Ksb + i * 512);
    gl_lds16(vt + kvbase + (size_t)row * T_ + kt * 64 + sblk * 8, Vsb + i * 512);
  }
}

__global__ __launch_bounds__(256) void attn_kernel(const u16* __restrict__ q, const u16* __restrict__ k,
                                                   const u16* __restrict__ vt, u16* __restrict__ o) {
  __shared__ __align__(16) u16 Ks[2][64 * 64];
  __shared__ __align__(16) u16 Vs[2][64 * 64];
  __shared__ __align__(16) u16 Pl[4][2][16 * 64];   // per wave, per sub; 49152 B -> 3 blocks/CU
  int L = blockIdx.x;                                // 2560 blocks (2560 % 8 == 0)
  int W = (L & 7) * 320 + (L >> 3);
  int qt = W % 5;
  int bh = W / 5;
  int h = bh & 15, b = bh >> 4;
  int g = h >> 2;
  int tid = threadIdx.x;
  int w = tid >> 6, l = tid & 63;
  int lr = l & 15, lg = l >> 4;
  const size_t kvbase = ((size_t)(b * G_ + g)) * (T_ * 64);

  const bool okB = (qt < 4);                 // qt==4: rows 512..575 only (sub-A)
  const int qrA = qt * 128 + w * 16;
  const int qrB = okB ? (qrA + 64) : qrA;    // clamped (valid memory; results unstored)
  const u16* qpA = q + (((size_t)(b * H_ + h)) * T_ + qrA + lr) * 64;
  const u16* qpB = q + (((size_t)(b * H_ + h)) * T_ + qrB + lr) * 64;
  short8 qfA0 = *(const short8*)(qpA + lg * 8);
  short8 qfA1 = *(const short8*)(qpA + 32 + lg * 8);
  short8 qfB0 = *(const short8*)(qpB + lg * 8);
  short8 qfB1 = *(const short8*)(qpB + 32 + lg * 8);

  float lsA[4] = {0.f, 0.f, 0.f, 0.f}, lsB[4] = {0.f, 0.f, 0.f, 0.f};
  f32x4 oaccA[4], oaccB[4];
#pragma unroll
  for (int dt = 0; dt < 4; ++dt) {
    oaccA[dt] = (f32x4){0.f, 0.f, 0.f, 0.f};
    oaccB[dt] = (f32x4){0.f, 0.f, 0.f, 0.f};
  }

  const int srow = l >> 3;                 // 0..7
  const int sblk = (l & 7) ^ (srow & 7);   // pre-swizzled source block

  stage_kv(k, vt, kvbase, 0, &Ks[0][0], &Vs[0][0], w, srow, sblk);
  WAITBAR(0)

  int cur = 0;
  for (int kt = 0; kt < 9; ++kt) {
    if (kt < 8)
      stage_kv(k, vt, kvbase, kt + 1, &Ks[cur ^ 1][0], &Vs[cur ^ 1][0], w, srow, sblk);

    // QK^T for both subs; kf loaded ONCE per ct
    f32x4 sA[4], sB[4];
#pragma unroll
    for (int ct = 0; ct < 4; ++ct) {
      sA[ct] = (f32x4){0.f, 0.f, 0.f, 0.f};
      sB[ct] = (f32x4){0.f, 0.f, 0.f, 0.f};
      int row = ct * 16 + lr;
      int i0 = (0 * 4 + lg) ^ (row & 7);
      int i1 = (1 * 4 + lg) ^ (row & 7);
      short8 kf0 = *(const short8*)(&Ks[cur][row * 64 + i0 * 8]);
      short8 kf1 = *(const short8*)(&Ks[cur][row * 64 + i1 * 8]);
      sA[ct] = __builtin_amdgcn_mfma_f32_16x16x32_bf16(qfA0, kf0, sA[ct], 0, 0, 0);
      sA[ct] = __builtin_amdgcn_mfma_f32_16x16x32_bf16(qfA1, kf1, sA[ct], 0, 0, 0);
      sB[ct] = __builtin_amdgcn_mfma_f32_16x16x32_bf16(qfB0, kf0, sB[ct], 0, 0, 0);
      sB[ct] = __builtin_amdgcn_mfma_f32_16x16x32_bf16(qfB1, kf1, sB[ct], 0, 0, 0);
    }

    // softmax (no-max form) + swizzled P-write, per sub
    u16* plA = &Pl[w][0][0];
    u16* plB = &Pl[w][1][0];
#pragma unroll
    for (int ct = 0; ct < 4; ++ct) {
      float pA[4], pB[4];
#pragma unroll
      for (int r = 0; r < 4; ++r) { pA[r] = exp2v(sA[ct][r]); pB[r] = exp2v(sB[ct][r]); }
#pragma unroll
      for (int r = 0; r < 4; ++r) { lsA[r] += pA[r]; lsB[r] += pB[r]; }
#pragma unroll
      for (int r = 0; r < 4; ++r) {
        int prow = lg * 4 + r;
        int pblk = (ct * 2 + (lr >> 3)) ^ (prow & 7);
        int off = prow * 64 + pblk * 8 + (lr & 7);
        plA[off] = (u16)((__float_as_uint(pA[r]) + 0x8000u) >> 16);
        plB[off] = (u16)((__float_as_uint(pB[r]) + 0x8000u) >> 16);
      }
    }
    __builtin_amdgcn_sched_barrier(0);
    asm volatile("s_waitcnt lgkmcnt(0)" ::: "memory");
    __builtin_amdgcn_sched_barrier(0);

    // PV for both subs; vf loaded ONCE per (c,dt)
#pragma unroll
    for (int c = 0; c < 2; ++c) {
      int rblk = (c * 4 + lg) ^ (lr & 7);
      short8 pfA = *(const short8*)(plA + lr * 64 + rblk * 8);
      short8 pfB = *(const short8*)(plB + lr * 64 + rblk * 8);
#pragma unroll
      for (int dt = 0; dt < 4; ++dt) {
        int row = dt * 16 + lr;
        int blk = (c * 4 + lg) ^ (row & 7);
        short8 vf = *(const short8*)(&Vs[cur][row * 64 + blk * 8]);
        oaccA[dt] = __builtin_amdgcn_mfma_f32_16x16x32_bf16(pfA, vf, oaccA[dt], 0, 0, 0);
        oaccB[dt] = __builtin_amdgcn_mfma_f32_16x16x32_bf16(pfB, vf, oaccB[dt], 0, 0, 0);
      }
    }

    if (kt < 8) {
      WAITBAR(0)
      cur ^= 1;
    }
  }

  // final row-sum reduces (wave-local), per sub
#pragma unroll
  for (int mk = 1; mk <= 8; mk <<= 1)
#pragma unroll
    for (int r = 0; r < 4; ++r) { lsA[r] += __shfl_xor(lsA[r], mk); lsB[r] += __shfl_xor(lsB[r], mk); }

  // normalize + store attn-out [B,T,H*HD] bf16
#pragma unroll
  for (int dt = 0; dt < 4; ++dt)
#pragma unroll
    for (int r = 0; r < 4; ++r) {
      int trowA = qt * 128 + w * 16 + lg * 4 + r;
      float vA = oaccA[dt][r] / lsA[r];
      o[((size_t)b * T_ + trowA) * 1024 + h * 64 + dt * 16 + lr] = f2bf(vA);
    }
  if (okB) {
#pragma unroll
    for (int dt = 0; dt < 4; ++dt)
#pragma unroll
      for (int r = 0; r < 4; ++r) {
        int trowB = qt * 128 + 64 + w * 16 + lg * 4 + r;
        float vB = oaccB[dt][r] / lsB[r];
        o[((size_t)b * T_ + trowB) * 1024 + h * 64 + dt * 16 + lr] = f2bf(vB);
      }
  }
}

extern "C" void kernel_launch(void* const* d_in, const int* in_sizes, int n_in,
                              void* d_out, int out_size, void* d_ws, size_t ws_size,
                              hipStream_t stream) {
  const float* x = (const float*)d_in[0];
  const float* wqkv = (const float*)d_in[1];
  const float* wo = (const float*)d_in[2];
  float* out = (float*)d_out;

  u16* ws = (u16*)d_ws;
  u16* xb = ws;                                  // reused as attn-out
  u16* wqkvb = xb + (size_t)BT * DM;
  u16* wob = wqkvb + (size_t)NQKV * DM;
  u16* qb = wob + (size_t)DM * DM;
  u16* kb = qb + (size_t)BT * DM;
  u16* vtb = kb + (size_t)B_ * G_ * T_ * 64;
  float4* tab = (float4*)(vtb + (size_t)B_ * G_ * T_ * 64);
  u16* ob = xb;  // alias: x-bf16 is dead after gemm<0>

  const int prep_items = NX4 + NQ4 + NW4 + T_ * FD;
  prep_kernel<<<(prep_items + 255) / 256, 256, 0, stream>>>(
      (const float4*)x, (const float4*)wqkv, (const float4*)wo, xb, wqkvb, wob, tab);
  gemm_nt<0, 12><<<dim3(12, 144), 256, 0, stream>>>(xb, wqkvb, qb, kb, vtb, nullptr, tab);
  attn_kernel<<<B_ * H_ * 5, 256, 0, stream>>>(qb, kb, vtb, ob);
  gemm_nt<1, 8><<<dim3(8, 144), 256, 0, stream>>>(ob, wob, nullptr, nullptr, nullptr, out, nullptr);
}